// Round 1
// 16101.282 us; speedup vs baseline: 1.0048x; 1.0048x over previous
//
#include <hip/hip_runtime.h>
#include <math.h>

typedef unsigned int u32;
typedef unsigned long long u64;
typedef unsigned short u16;
typedef __attribute__((ext_vector_type(8))) short short8;
typedef __attribute__((ext_vector_type(4))) float f4;
typedef __attribute__((ext_vector_type(4))) u32 u32x4;

#define Ssz 2048
#define Bsz 64
#define Isz 256
#define Hsz 512
#define KC0 24   // 768/32 k-chunks, layer0 (256 x + 512 h)
#define KC1 32   // 1024/32 k-chunks, layer1 (512 y0 + 512 h1)

// ws layout (bytes). Weights PACKED u32 = bf16hi | bf16lo<<16, B-frag order.
#define WB0_OFF   0u
#define WB1_OFF   1572864u
#define BIAS0_OFF 3670016u
#define BIAS1_OFF 3672064u
#define FLAGS_OFF 3674112u   // per m: 256B region; flags1[8] @+64
#define H0_OFF    3675136u   // [slot=3][m=4] x 32KB, chunk-major packed u32
#define H1_OFF    4068352u   // [slot=2][m=4] x 32KB
// end: 4330496

#define MFMA(a, b, c) __builtin_amdgcn_mfma_f32_16x16x32_bf16(a, b, c, 0, 0, 0)

__device__ __forceinline__ u16 f2bf(float f) {
  union { float f; u32 u; } v; v.f = f;
  u32 r = v.u + 0x7FFFu + ((v.u >> 16) & 1u);
  return (u16)(r >> 16);
}
__device__ __forceinline__ float bf2f(u16 h) {
  union { u32 u; float f; } v; v.u = ((u32)h) << 16;
  return v.f;
}
__device__ __forceinline__ u32 packbf(float f) {
  u16 hi = f2bf(f);
  u16 lo = f2bf(f - bf2f(hi));
  return (u32)hi | ((u32)lo << 16);
}
__device__ __forceinline__ void unpack2(u32 w0, u32 w1, u32& hi, u32& lo) {
  hi = __builtin_amdgcn_perm(w1, w0, 0x05040100u);
  lo = __builtin_amdgcn_perm(w1, w0, 0x07060302u);
}
__device__ __forceinline__ void cvt2(float a, float b, u32& hi, u32& lo) {
  u16 ha = f2bf(a), hb = f2bf(b);
  u16 la = f2bf(a - bf2f(ha)), lb = f2bf(b - bf2f(hb));
  hi = (u32)ha | ((u32)hb << 16);
  lo = (u32)la | ((u32)lb << 16);
}
__device__ __forceinline__ float ftanh(float xx) {
  float x = fminf(20.f, fmaxf(-20.f, xx));
  float e = __expf(2.f * x);
  return (e - 1.f) / (e + 1.f);
}

union frag { short8 s; u32 w[4]; };

// LLC-coherent (agent-scope, L2-bypass) accessors
__device__ __forceinline__ u64 ald64(const u64* p) {
  return __hip_atomic_load(p, __ATOMIC_RELAXED, __HIP_MEMORY_SCOPE_AGENT);
}
__device__ __forceinline__ u32 ald32(const u32* p) {
  return __hip_atomic_load(p, __ATOMIC_RELAXED, __HIP_MEMORY_SCOPE_AGENT);
}
__device__ __forceinline__ void ast32(u32* p, u32 v) {
  __hip_atomic_store(p, v, __ATOMIC_RELAXED, __HIP_MEMORY_SCOPE_AGENT);
}

// Self-validating spin-load: every stored u32 carries a 1-bit step tag at
// bit16 (LSB of lo-bf16). A wave accepts its whole 16KB read only when all
// words carry the expected tag. Merges flag-poll + data-load into one flight.
__device__ __forceinline__ void spin_load(const u32* rb, int ks, int lane,
                                          u32 tag, u64 (&hb)[8][4]) {
  const u64 M = 0x0001000000010000ull;
  const u64 E = tag ? M : 0ull;
  while (1) {
    #pragma unroll
    for (int i = 0; i < 8; ++i) {
      const u64* pp = (const u64*)(rb + (2 * i + ks) * 512 + lane * 8);
      #pragma unroll
      for (int v = 0; v < 4; ++v) hb[i][v] = ald64(pp + v);
    }
    int ok = 1;
    #pragma unroll
    for (int i = 0; i < 8; ++i)
      #pragma unroll
      for (int v = 0; v < 4; ++v) ok &= (int)((hb[i][v] & M) == E);
    if (__all(ok)) break;
  }
}

__global__ void prep_weights(const float* __restrict__ Wih0, const float* __restrict__ Whh0,
                             const float* __restrict__ bih0, const float* __restrict__ bhh0,
                             const float* __restrict__ Wih1, const float* __restrict__ Whh1,
                             const float* __restrict__ bih1, const float* __restrict__ bhh1,
                             const int* __restrict__ mih0, const int* __restrict__ mhh0,
                             const int* __restrict__ mih1, const int* __restrict__ mhh1,
                             char* __restrict__ ws) {
  const int L0E = 768 * 512, L1E = 1024 * 512;
  const int TAGN = 3 * 32768;   // H0 slot0, H0 slot2, H1 slot0 tag-init
  int e = blockIdx.x * blockDim.x + threadIdx.x;
  if (e >= L0E + L1E + 1024 + TAGN) return;
  if (e < L0E) {
    int f = e >> 9, fe = e & 511;
    int lane = fe >> 3, j = fe & 7;
    int n = lane & 15, q = lane >> 4;
    int nt = f / KC0, kc = f % KC0;
    int u = nt * 16 + n, k = kc * 32 + q * 8 + j;
    float w;
    if (k < 256) w = Wih0[u * 256 + k] * (float)mih0[u * 256 + k];
    else         w = Whh0[u * 512 + (k - 256)] * (float)mhh0[u * 512 + (k - 256)];
    ((u32*)(ws + WB0_OFF))[e] = packbf(w);
  } else if (e < L0E + L1E) {
    int e1 = e - L0E;
    int f = e1 >> 9, fe = e1 & 511;
    int lane = fe >> 3, j = fe & 7;
    int n = lane & 15, q = lane >> 4;
    int nt = f >> 5, kc = f & 31;
    int u = nt * 16 + n, k = kc * 32 + q * 8 + j;
    float w;
    if (k < 512) w = Wih1[u * 512 + k] * (float)mih1[u * 512 + k];
    else         w = Whh1[u * 512 + (k - 512)] * (float)mhh1[u * 512 + (k - 512)];
    ((u32*)(ws + WB1_OFF))[e1] = packbf(w);
  } else if (e < L0E + L1E + 1024) {
    int b2 = e - L0E - L1E;
    if (b2 < 512) ((float*)(ws + BIAS0_OFF))[b2] = bih0[b2] + bhh0[b2];
    else          ((float*)(ws + BIAS1_OFF))[b2 - 512] = bih1[b2 - 512] + bhh1[b2 - 512];
  } else {
    // tag-init: value ~= 0 with tag bit (bit16) = 1. Slots whose first real
    // write carries tag0 must init to tag1 (so stale data is rejected);
    // H0 slot2 / H1 slot... H0 slot2 doubles as the valid h0[-1]=0 read.
    int ti = e - (L0E + L1E + 1024);
    u32* dst;
    if (ti < 32768)      dst = (u32*)(ws + H0_OFF) + ti;            // H0 slot 0
    else if (ti < 65536) dst = (u32*)(ws + H0_OFF) + 32768 + ti;    // H0 slot 2
    else                 dst = (u32*)(ws + H1_OFF) + (ti - 65536);  // H1 slot 0
    *dst = 0x00010000u;
  }
}

// H chunk-major layout per (slot,m) 32KB: elem (b local 0..15, u 0..511) at
// u32 index  c*512 + (b + 16*((u&31)>>3))*8 + (u&7),  c = u>>5.
// A consumer wave's chunk read = 64 lanes x 32B fully contiguous (2KB).

__device__ __forceinline__ void run0(const float* __restrict__ x, char* __restrict__ ws,
                                     int m, int p, int tid, float (*red)[256]) {
  const int w = tid >> 6, lane = tid & 63, n = lane & 15, q = lane >> 4;
  const int nt = p * 4 + (w & 3), ks = w >> 2;
  const int b0 = m * 16;
  const u32* WB = (const u32*)(ws + WB0_OFF);
  u32* flags1 = (u32*)(ws + FLAGS_OFF + m * 256) + 16;
  const float bs = ((const float*)(ws + BIAS0_OFF))[nt * 16 + n];

  // weights -> registers (96 VGPR): chunks kcg = 2i+ks
  short8 Whi[12], Wlo[12];
  #pragma unroll
  for (int i = 0; i < 12; ++i) {
    const int kcg = 2 * i + ks;
    const u32* pw = WB + ((nt * KC0 + kcg) * 64 + lane) * 8;
    u32x4 a = *(const u32x4*)pw;
    u32x4 b = *(const u32x4*)(pw + 4);
    frag h, l;
    unpack2(a.x, a.y, h.w[0], l.w[0]);
    unpack2(a.z, a.w, h.w[1], l.w[1]);
    unpack2(b.x, b.y, h.w[2], l.w[2]);
    unpack2(b.z, b.w, h.w[3], l.w[3]);
    Whi[i] = h.s; Wlo[i] = l.s;
  }

  f4 xp[4][2];
  auto loadx = [&](int t) {
    #pragma unroll
    for (int i = 0; i < 4; ++i) {
      const int kcg = 2 * i + ks;
      const float* sx = x + ((long)t * Bsz + b0 + n) * Isz + kcg * 32 + q * 8;
      xp[i][0] = *(const f4*)sx;
      xp[i][1] = *(const f4*)(sx + 4);
    }
  };
  short8 Axh[4], Axl[4];
  auto cvtx = [&]() {
    #pragma unroll
    for (int i = 0; i < 4; ++i) {
      frag h, l;
      #pragma unroll
      for (int v = 0; v < 2; ++v) {
        f4 f = xp[i][v];
        cvt2(f.x, f.y, h.w[2 * v], l.w[2 * v]);
        cvt2(f.z, f.w, h.w[2 * v + 1], l.w[2 * v + 1]);
      }
      Axh[i] = h.s; Axl[i] = l.s;
    }
  };
  loadx(0); cvtx();

  const int cst = (nt * 16 + n) >> 5;           // store chunk (const per wave)
  const int qp = ((nt * 2) + (n >> 3)) & 3;
  const int jj = n & 7;
  int last1 = 0;                                // cached flags1 snapshot (tid0)

  for (int t = 0; t < Ssz; ++t) {
    // x-part MFMAs first (independent of h); 2 independent acc chains
    f4 acc0 = {0.f, 0.f, 0.f, 0.f}, acc1 = {0.f, 0.f, 0.f, 0.f};
    #pragma unroll
    for (int i = 0; i < 4; ++i) {
      acc0 = MFMA(Axh[i], Whi[i], acc0);
      acc1 = MFMA(Axh[i], Wlo[i], acc1);
      acc0 = MFMA(Axl[i], Whi[i], acc0);
    }
    loadx(t + 1 < Ssz ? t + 1 : t);   // prefetch next x; overlaps the spin
    // h0[t-1]: parity-validated spin (no flag hop, no barrier release)
    const u32* rb = (const u32*)(ws + H0_OFF) + (((t + 2) % 3) * 4 + m) * 8192;
    u64 hb[8][4];
    spin_load(rb, ks, lane, (u32)((t + 1) & 1), hb);
    #pragma unroll
    for (int i = 0; i < 8; ++i) {
      frag h, l;
      #pragma unroll
      for (int v = 0; v < 4; ++v)
        unpack2((u32)hb[i][v], (u32)(hb[i][v] >> 32), h.w[v], l.w[v]);
      acc0 = MFMA(h.s, Whi[4 + i], acc0);
      acc1 = MFMA(h.s, Wlo[4 + i], acc1);
      acc0 = MFMA(l.s, Whi[4 + i], acc0);
    }
    f4 acc = acc0 + acc1;
    // L1->L0 slot backpressure: ensure L1 finished reading h0[t-3] before we
    // overwrite its slot. Snapshot-cached; usually skipped entirely.
    if (tid == 0 && last1 < t - 2) {
      const int tgt = t - 2;
      while (1) {
        int mn = 0x7fffffff;
        #pragma unroll
        for (int i = 0; i < 8; ++i) { int f = (int)ald32(flags1 + i); if (f < mn) mn = f; }
        if (mn >= tgt) { last1 = mn; break; }
      }
    }
    // 2-way K reduction + tanh + h0 store (tag embedded; fire-and-forget)
    *(f4*)&red[w][lane * 4] = acc;
    __syncthreads();
    if (w < 4) {
      u32* wb = (u32*)(ws + H0_OFF) + ((t % 3) * 4 + m) * 8192;
      const u32 tb = (u32)(t & 1) << 16;
      f4 s0 = *(f4*)&red[w][lane * 4];
      f4 s1 = *(f4*)&red[w + 4][lane * 4];
      #pragma unroll
      for (int r = 0; r < 4; ++r) {
        float val = ftanh(bs + s0[r] + s1[r]);
        u32 pv = (packbf(val) & 0xFFFEFFFFu) | tb;
        ast32(wb + cst * 512 + ((q * 4 + r) + 16 * qp) * 8 + jj, pv);
      }
    }
    __syncthreads();
    cvtx();                                   // next x (loads already landed)
  }
}

__device__ __forceinline__ void run1(char* __restrict__ ws, float* __restrict__ out,
                                     int m, int p, int tid, float (*red)[256]) {
  const int w = tid >> 6, lane = tid & 63, n = lane & 15, q = lane >> 4;
  const int nt = p * 4 + (w & 3), ks = w >> 2;
  const int b0 = m * 16;
  const u32* WB = (const u32*)(ws + WB1_OFF);
  u32* flags1 = (u32*)(ws + FLAGS_OFF + m * 256) + 16;
  const float bs = ((const float*)(ws + BIAS1_OFF))[nt * 16 + n];

  short8 Whi[16], Wlo[16];   // 128 VGPR
  #pragma unroll
  for (int i = 0; i < 16; ++i) {
    const int kcg = 2 * i + ks;
    const u32* pw = WB + ((nt * KC1 + kcg) * 64 + lane) * 8;
    u32x4 a = *(const u32x4*)pw;
    u32x4 b = *(const u32x4*)(pw + 4);
    frag h, l;
    unpack2(a.x, a.y, h.w[0], l.w[0]);
    unpack2(a.z, a.w, h.w[1], l.w[1]);
    unpack2(b.x, b.y, h.w[2], l.w[2]);
    unpack2(b.z, b.w, h.w[3], l.w[3]);
    Whi[i] = h.s; Wlo[i] = l.s;
  }

  const int cst = (nt * 16 + n) >> 5;
  const int qp = ((nt * 2) + (n >> 3)) & 3;
  const int jj = n & 7;

  for (int t = 1; t <= Ssz; ++t) {
    f4 acc0 = {0.f, 0.f, 0.f, 0.f}, acc1 = {0.f, 0.f, 0.f, 0.f};
    // phase B FIRST: y0[t-1] (L0 runs ahead -> usually ready immediately);
    // its MFMAs overlap the in-flight h1[t-1] stores from our own group.
    {
      const u32* rb = (const u32*)(ws + H0_OFF) + (((t - 1) % 3) * 4 + m) * 8192;
      u64 hb[8][4];
      spin_load(rb, ks, lane, (u32)((t - 1) & 1), hb);
      #pragma unroll
      for (int i = 0; i < 8; ++i) {
        frag h, l;
        #pragma unroll
        for (int v = 0; v < 4; ++v)
          unpack2((u32)hb[i][v], (u32)(hb[i][v] >> 32), h.w[v], l.w[v]);
        acc0 = MFMA(h.s, Whi[i], acc0);
        acc1 = MFMA(h.s, Wlo[i], acc1);
        acc0 = MFMA(l.s, Whi[i], acc0);
      }
    }
    // phase A: own recurrence h1[t-1]
    {
      const u32* rb = (const u32*)(ws + H1_OFF) + ((t & 1) * 4 + m) * 8192;
      u64 hb[8][4];
      spin_load(rb, ks, lane, (u32)(((t - 1) >> 1) & 1), hb);
      #pragma unroll
      for (int i = 0; i < 8; ++i) {
        frag h, l;
        #pragma unroll
        for (int v = 0; v < 4; ++v)
          unpack2((u32)hb[i][v], (u32)(hb[i][v] >> 32), h.w[v], l.w[v]);
        acc0 = MFMA(h.s, Whi[8 + i], acc0);
        acc1 = MFMA(h.s, Wlo[8 + i], acc1);
        acc0 = MFMA(l.s, Whi[8 + i], acc0);
      }
    }
    f4 acc = acc0 + acc1;
    *(f4*)&red[w][lane * 4] = acc;
    __syncthreads();
    // all waves' reads validated -> release L0's slot backpressure early
    // (flags1 now means "L1 step t reads done", which is all L0 must wait on)
    if (tid == 0) ast32(flags1 + p, (u32)t);
    if (w < 4) {
      u32* wb = (u32*)(ws + H1_OFF) + (((t - 1) & 1) * 4 + m) * 8192;
      const u32 tb = (u32)((t >> 1) & 1) << 16;
      f4 s0 = *(f4*)&red[w][lane * 4];
      f4 s1 = *(f4*)&red[w + 4][lane * 4];
      #pragma unroll
      for (int r = 0; r < 4; ++r) {
        float val = ftanh(bs + s0[r] + s1[r]);
        u32 pv = (packbf(val) & 0xFFFEFFFFu) | tb;
        ast32(wb + cst * 512 + ((q * 4 + r) + 16 * qp) * 8 + jj, pv);
        if (t == Ssz) out[(b0 + q * 4 + r) * Hsz + nt * 16 + n] = val;
      }
    }
    __syncthreads();
  }
}

__global__ __launch_bounds__(512, 2) void rnn_persist(const float* __restrict__ x,
                                                      char* __restrict__ ws,
                                                      float* __restrict__ out) {
  __shared__ float red[8][256];
  const int tid = threadIdx.x;
  const int wg = blockIdx.x;
  const int m = (wg >> 3) & 3, p = wg & 7;
  if (wg < 32) run0(x, ws, m, p, tid, red);
  else         run1(ws, out, m, p, tid, red);
}

extern "C" void kernel_launch(void* const* d_in, const int* in_sizes, int n_in,
                              void* d_out, int out_size, void* d_ws, size_t ws_size,
                              hipStream_t stream) {
  const float* x    = (const float*)d_in[0];
  const float* Wih0 = (const float*)d_in[1];
  const float* Whh0 = (const float*)d_in[2];
  const float* bih0 = (const float*)d_in[3];
  const float* bhh0 = (const float*)d_in[4];
  const float* Wih1 = (const float*)d_in[5];
  const float* Whh1 = (const float*)d_in[6];
  const float* bih1 = (const float*)d_in[7];
  const float* bhh1 = (const float*)d_in[8];
  const int* mih0   = (const int*)d_in[9];
  const int* mhh0   = (const int*)d_in[10];
  const int* mih1   = (const int*)d_in[11];
  const int* mhh1   = (const int*)d_in[12];
  char* ws = (char*)d_ws;

  // zero flags + H0(3 slots) + H1(2 slots); prep then overwrites tag-init slots
  hipMemsetAsync(ws + FLAGS_OFF, 0, 1024 + 393216 + 262144, stream);

  const int tot = 768 * 512 + 1024 * 512 + 1024 + 3 * 32768;
  prep_weights<<<(tot + 255) / 256, 256, 0, stream>>>(
      Wih0, Whh0, bih0, bhh0, Wih1, Whh1, bih1, bhh1,
      mih0, mhh0, mih1, mhh1, ws);

  rnn_persist<<<64, 512, 0, stream>>>(x, ws, (float*)d_out);
}